// Round 9
// baseline (196.096 us; speedup 1.0000x reference)
//
#include <hip/hip_runtime.h>

#define LBL 32
#define NPIX (736 * 736)   // 541696
#define NQ (NPIX / 4)      // 135424 float4-quads per batch
#define QPB 512            // quads per block (2 per thread)
#define NBA 265            // ceil(NQ/QPB); block 264 has only its first quad-set valid
#define BATCH 8
#define DELTA_AGG 0.5f
#define DELTA_DIS 1.5f
#define REG_W 0.001f

// ws layout (float indices), ~6.3 MB — all slots plain-stored before read:
//  lab:   [0, +8*NQ)              packed mask-only labels, 4 px per uint32
//  partA: [PA_BASE, +8*NBA*160)   block-major per (batch,block): cnt_k[32], sum[128]
//  red:   [RED_BASE, +8*256)      per batch RAW totals: cnt_k[32], sumtot[128]
//  partC: [PC_BASE, +8*NBA*64)    block-major per (batch,block): val[32], cnt_a[32]
#define LAB_BASE 0
#define PA_BASE (BATCH * NQ)                   // 1083392
#define RED_BASE (PA_BASE + BATCH * NBA * 160) // 1422592
#define PC_BASE (RED_BASE + BATCH * 256)       // 1424640
// end: PC_BASE + 8*265*64 = 1560320 floats = 6.24 MB

// ===== Pass A: kernel-region count + emb sums; spill packed labels ==========
__global__ __launch_bounds__(256) void kA(
    const float* __restrict__ emb, const int* __restrict__ inst,
    const float* __restrict__ kern, const float* __restrict__ mask,
    float* __restrict__ ws) {
  const int b = blockIdx.y;
  const int t = threadIdx.x;
  __shared__ float s_cnt[LBL];   // [0] is the "saw label 0" flag
  __shared__ float s_sum[LBL * 4];
  if (t < LBL) s_cnt[t] = 0.f;
  if (t < LBL * 4) s_sum[t] = 0.f;
  __syncthreads();

  const long base = (long)b * NPIX;
  const float* eb = emb + (long)b * 4 * NPIX;
  const int4* ip = (const int4*)(inst + base);
  const float4* kp = (const float4*)(kern + base);
  const float4* mp = (const float4*)(mask + base);
  const float4* p0 = (const float4*)(eb);
  const float4* p1 = (const float4*)(eb + NPIX);
  const float4* p2 = (const float4*)(eb + 2 * NPIX);
  const float4* p3 = (const float4*)(eb + 3 * NPIX);

  const int q0 = blockIdx.x * QPB + t;
  const int q1 = q0 + 256;
  const bool v1 = (q1 < NQ);  // block-uniform: false only for block 264

  // ---- issue ALL loads up front (max MLP: up to 14 x 16B in flight) ----
  const int4 iva = ip[q0];
  const float4 kva = kp[q0], mva = mp[q0];
  const float4 ea0 = p0[q0], ea1 = p1[q0], ea2 = p2[q0], ea3 = p3[q0];
  int4 ivb;
  float4 kvb, mvb, eb0, eb1, eb2, eb3;
  if (v1) {
    ivb = ip[q1]; kvb = kp[q1]; mvb = mp[q1];
    eb0 = p0[q1]; eb1 = p1[q1]; eb2 = p2[q1]; eb3 = p3[q1];
  }

  bool has0 = false;
  unsigned int* labp = (unsigned int*)(ws + LAB_BASE) + (size_t)b * NQ;

  {
    const int labs[4] = {iva.x, iva.y, iva.z, iva.w};
    const float ks[4] = {kva.x, kva.y, kva.z, kva.w};
    const float ms[4] = {mva.x, mva.y, mva.z, mva.w};
    const float c0[4] = {ea0.x, ea0.y, ea0.z, ea0.w};
    const float c1[4] = {ea1.x, ea1.y, ea1.z, ea1.w};
    const float c2[4] = {ea2.x, ea2.y, ea2.z, ea2.w};
    const float c3[4] = {ea3.x, ea3.y, ea3.z, ea3.w};
    unsigned int labw = 0;
#pragma unroll
    for (int j = 0; j < 4; j++) {
      const bool m = ms[j] > 0.5f;
      const int li = m ? labs[j] : 0;
      const int lk = (m && ks[j] > 0.5f) ? labs[j] : 0;
      labw |= ((unsigned int)li) << (8 * j);
      if (lk > 0) {
        atomicAdd(&s_cnt[lk], 1.0f);
        atomicAdd(&s_sum[lk * 4 + 0], c0[j]);
        atomicAdd(&s_sum[lk * 4 + 1], c1[j]);
        atomicAdd(&s_sum[lk * 4 + 2], c2[j]);
        atomicAdd(&s_sum[lk * 4 + 3], c3[j]);
      } else {
        has0 = true;
      }
    }
    labp[q0] = labw;
  }
  if (v1) {
    const int labs[4] = {ivb.x, ivb.y, ivb.z, ivb.w};
    const float ks[4] = {kvb.x, kvb.y, kvb.z, kvb.w};
    const float ms[4] = {mvb.x, mvb.y, mvb.z, mvb.w};
    const float c0[4] = {eb0.x, eb0.y, eb0.z, eb0.w};
    const float c1[4] = {eb1.x, eb1.y, eb1.z, eb1.w};
    const float c2[4] = {eb2.x, eb2.y, eb2.z, eb2.w};
    const float c3[4] = {eb3.x, eb3.y, eb3.z, eb3.w};
    unsigned int labw = 0;
#pragma unroll
    for (int j = 0; j < 4; j++) {
      const bool m = ms[j] > 0.5f;
      const int li = m ? labs[j] : 0;
      const int lk = (m && ks[j] > 0.5f) ? labs[j] : 0;
      labw |= ((unsigned int)li) << (8 * j);
      if (lk > 0) {
        atomicAdd(&s_cnt[lk], 1.0f);
        atomicAdd(&s_sum[lk * 4 + 0], c0[j]);
        atomicAdd(&s_sum[lk * 4 + 1], c1[j]);
        atomicAdd(&s_sum[lk * 4 + 2], c2[j]);
        atomicAdd(&s_sum[lk * 4 + 3], c3[j]);
      } else {
        has0 = true;
      }
    }
    labp[q1] = labw;
  }

  if (has0) s_cnt[0] = 1.0f;  // benign race: all writers store 1
  __syncthreads();
  // block-major coalesced partial store (no write amplification)
  float* po = ws + PA_BASE + ((size_t)b * NBA + blockIdx.x) * 160;
  if (t < 160) po[t] = (t < 32) ? s_cnt[t] : s_sum[t - 32];
}

// ===== Reduce A: one wave per (batch,elem), strided gather from L2 ==========
__global__ __launch_bounds__(256) void kB(float* __restrict__ ws) {
  const int b = blockIdx.y;
  const int col = blockIdx.x * 4 + (threadIdx.x >> 6);  // 40 blocks x 4 waves = 160
  const int lane = threadIdx.x & 63;
  const float* pa = ws + PA_BASE + (size_t)b * NBA * 160 + col;
  float s = 0.f;
  for (int g = lane; g < NBA; g += 64) s += pa[(size_t)g * 160];
#pragma unroll
  for (int o = 32; o > 0; o >>= 1) s += __shfl_down(s, o);
  if (lane == 0) ws[RED_BASE + b * 256 + col] = s;  // raw totals
}

// ===== Pass C: aggregation sums + cnt_a from emb (L3-hot) + labels ==========
__global__ __launch_bounds__(256) void kC(
    const float* __restrict__ emb, float* __restrict__ ws) {
  const int b = blockIdx.y;
  const int t = threadIdx.x;
  __shared__ float s_mean[LBL * 4];
  __shared__ float s_val[LBL];
  __shared__ float s_cta[LBL];
  const float* rd = ws + RED_BASE + b * 256;
  if (t < LBL * 4) {
    const int l = t >> 2;
    s_mean[t] = (l == 0) ? 0.f : rd[32 + t] / fmaxf(rd[l], 1.0f);
  }
  if (t < LBL) {
    s_val[t] = 0.f;
    s_cta[t] = 0.f;
  }
  __syncthreads();

  const float* ebase = emb + (long)b * 4 * NPIX;
  const float4* p0 = (const float4*)(ebase);
  const float4* p1 = (const float4*)(ebase + NPIX);
  const float4* p2 = (const float4*)(ebase + 2 * NPIX);
  const float4* p3 = (const float4*)(ebase + 3 * NPIX);
  const unsigned int* labp = (const unsigned int*)(ws + LAB_BASE) + (size_t)b * NQ;

  const int q0 = blockIdx.x * QPB + t;
  const int q1 = q0 + 256;
  const bool v1 = (q1 < NQ);

  const unsigned int lwa = labp[q0];
  const float4 ea0 = p0[q0], ea1 = p1[q0], ea2 = p2[q0], ea3 = p3[q0];
  unsigned int lwb = 0;
  float4 eb0, eb1, eb2, eb3;
  if (v1) {
    lwb = labp[q1];
    eb0 = p0[q1]; eb1 = p1[q1]; eb2 = p2[q1]; eb3 = p3[q1];
  }

  {
    const float c0[4] = {ea0.x, ea0.y, ea0.z, ea0.w};
    const float c1[4] = {ea1.x, ea1.y, ea1.z, ea1.w};
    const float c2[4] = {ea2.x, ea2.y, ea2.z, ea2.w};
    const float c3[4] = {ea3.x, ea3.y, ea3.z, ea3.w};
#pragma unroll
    for (int j = 0; j < 4; j++) {
      const int li = (lwa >> (8 * j)) & 0xFF;
      if (li > 0) {
        const float d0 = c0[j] - s_mean[li * 4 + 0];
        const float d1 = c1[j] - s_mean[li * 4 + 1];
        const float d2 = c2[j] - s_mean[li * 4 + 2];
        const float d3 = c3[j] - s_mean[li * 4 + 3];
        const float sq = d0 * d0 + d1 * d1 + d2 * d2 + d3 * d3;
        const float dist = (sq > 0.f) ? sqrtf(sq) : 0.f;
        const float tt = fmaxf(dist - DELTA_AGG, 0.f);
        atomicAdd(&s_val[li], logf(fmaf(tt, tt, 1.0f)));
        atomicAdd(&s_cta[li], 1.0f);
      }
    }
  }
  if (v1) {
    const float c0[4] = {eb0.x, eb0.y, eb0.z, eb0.w};
    const float c1[4] = {eb1.x, eb1.y, eb1.z, eb1.w};
    const float c2[4] = {eb2.x, eb2.y, eb2.z, eb2.w};
    const float c3[4] = {eb3.x, eb3.y, eb3.z, eb3.w};
#pragma unroll
    for (int j = 0; j < 4; j++) {
      const int li = (lwb >> (8 * j)) & 0xFF;
      if (li > 0) {
        const float d0 = c0[j] - s_mean[li * 4 + 0];
        const float d1 = c1[j] - s_mean[li * 4 + 1];
        const float d2 = c2[j] - s_mean[li * 4 + 2];
        const float d3 = c3[j] - s_mean[li * 4 + 3];
        const float sq = d0 * d0 + d1 * d1 + d2 * d2 + d3 * d3;
        const float dist = (sq > 0.f) ? sqrtf(sq) : 0.f;
        const float tt = fmaxf(dist - DELTA_AGG, 0.f);
        atomicAdd(&s_val[li], logf(fmaf(tt, tt, 1.0f)));
        atomicAdd(&s_cta[li], 1.0f);
      }
    }
  }
  __syncthreads();
  float* po = ws + PC_BASE + ((size_t)b * NBA + blockIdx.x) * 64;
  if (t < 64) po[t] = (t < 32) ? s_val[t] : s_cta[t - 32];
}

// ===== Reduce C + finalize (one 1024-thread block per batch) ================
__global__ __launch_bounds__(1024) void kD(const float* __restrict__ ws,
                                           float* __restrict__ out) {
  const int b = blockIdx.x;
  const int t = threadIdx.x;
  const int col = t >> 4, sub = t & 15;  // 64 cols x 16 chunks
  const float* pc = ws + PC_BASE + (size_t)b * NBA * 64 + col;
  float s = 0.f;
  for (int g = sub; g < NBA; g += 16) s += pc[(size_t)g * 64];
  __shared__ float red[64][17];
  red[col][sub] = s;

  const float* rd = ws + RED_BASE + b * 256;
  __shared__ float sm[LBL * 4];
  __shared__ float scc[LBL];
  if (t >= 512 && t < 640) {
    const int e = t - 512, l = e >> 2;
    sm[e] = (l == 0) ? 0.f : rd[32 + e] / fmaxf(rd[l], 1.0f);
  } else if (t >= 640 && t < 672) {
    scc[t - 640] = rd[t - 640];
  }
  __syncthreads();
  __shared__ float svca[64];  // [0,32)=sum_v, [32,64)=cnt_a
  if (t < 64) {
    float v = 0.f;
#pragma unroll
    for (int k = 0; k < 16; k++) v += red[t][k];
    svca[t] = v;
  }
  __syncthreads();

  if (t < 64) {  // wave 0 only
    const int lane = t;
    const bool pres = (lane < LBL) && (scc[lane & 31] > 0.f);
    const unsigned long long bal_p = __ballot(pres);
    const int num_instance = __popcll(bal_p);
    const bool nz = pres && (lane > 0);
    const unsigned long long bal_nz = __ballot(nz);

    float agg = 0.f;
    if (nz) agg = svca[lane] / fmaxf(svca[32 + lane], 1.0f);

    float reg = 0.f;
    if (pres) {
      float sq = 0.f;
#pragma unroll
      for (int d = 0; d < 4; d++) sq += sm[lane * 4 + d] * sm[lane * 4 + d];
      const float nrm = (sq > 0.f) ? sqrtf(sq) : 0.f;
      reg = logf(nrm + 1.0f);
    }

    float dis = 0.f, npair = 0.f;
    for (int pi = lane; pi < LBL * LBL; pi += 64) {
      const int i = pi >> 5, j = pi & 31;
      if (i != j && ((bal_nz >> i) & 1ull) && ((bal_nz >> j) & 1ull)) {
        float sq = 0.f;
#pragma unroll
        for (int d = 0; d < 4; d++) {
          const float df = sm[i * 4 + d] - sm[j * 4 + d];
          sq += df * df;
        }
        const float pdist = (sq > 0.f) ? sqrtf(sq) : 0.f;
        const float tt = fmaxf(2.0f * DELTA_DIS - pdist, 0.f);
        dis += logf(fmaf(tt, tt, 1.0f));
        npair += 1.0f;
      }
    }

#pragma unroll
    for (int o = 32; o > 0; o >>= 1) {
      agg += __shfl_down(agg, o);
      reg += __shfl_down(reg, o);
      dis += __shfl_down(dis, o);
      npair += __shfl_down(npair, o);
    }

    if (lane == 0) {
      const float l_agg = agg / fmaxf((float)(num_instance - 1), 1.0f);
      const float l_dis = (num_instance > 2) ? dis / fmaxf(npair, 1.0f) : 0.f;
      const float l_reg = reg / fmaxf((float)num_instance, 1.0f) * REG_W;
      const float loss = l_agg + l_dis + l_reg;
      out[b] = (num_instance <= 1) ? 0.f : loss;
    }
  }
}

extern "C" void kernel_launch(void* const* d_in, const int* in_sizes, int n_in,
                              void* d_out, int out_size, void* d_ws,
                              size_t ws_size, hipStream_t stream) {
  const float* emb = (const float*)d_in[0];
  const int* instance = (const int*)d_in[1];
  const float* kern = (const float*)d_in[2];
  const float* mask = (const float*)d_in[3];
  float* out = (float*)d_out;
  float* ws = (float*)d_ws;

  dim3 gridA(NBA, BATCH);  // 2120 blocks, 2 quads per thread
  kA<<<gridA, 256, 0, stream>>>(emb, instance, kern, mask, ws);
  dim3 gridB(40, BATCH);   // one wave per (batch, elem) column
  kB<<<gridB, 256, 0, stream>>>(ws);
  kC<<<gridA, 256, 0, stream>>>(emb, ws);
  kD<<<BATCH, 1024, 0, stream>>>(ws, out);
}